// Round 1
// baseline (346.391 us; speedup 1.0000x reference)
//
#include <hip/hip_runtime.h>
#include <hip/hip_bf16.h>
#include <cstdint>

// ---------- types ----------
typedef __attribute__((ext_vector_type(8))) __bf16 bf16x8;
typedef __attribute__((ext_vector_type(4))) float  f32x4;

// float -> bf16 round-to-nearest-even (no NaN handling needed; inputs are finite)
__device__ __forceinline__ unsigned short f2bf(float x) {
    union { float f; unsigned u; } v; v.f = x;
    unsigned r = v.u + 0x7fffu + ((v.u >> 16) & 1u);
    return (unsigned short)(r >> 16);
}

__device__ __forceinline__ void gld_lds16(const unsigned short* g, unsigned short* l) {
    __builtin_amdgcn_global_load_lds(
        (const __attribute__((address_space(1))) unsigned int*)g,
        (__attribute__((address_space(3))) unsigned int*)l,
        16, 0, 0);
}

// ---------- P0: fp32 -> bf16 convert ----------
__global__ void cvt_kernel(const float* __restrict__ in, unsigned short* __restrict__ out, int n4) {
    int i = blockIdx.x * blockDim.x + threadIdx.x;
    if (i < n4) {
        float4 f = ((const float4*)in)[i];
        ushort4 o;
        o.x = f2bf(f.x); o.y = f2bf(f.y); o.z = f2bf(f.z); o.w = f2bf(f.w);
        ((ushort4*)out)[i] = o;
    }
}

// ---------- P1: transpose-convert 1024x1024 fp32 W[k][n] -> bf16 out[n][k] ----------
__global__ void wtrans_kernel(const float* __restrict__ W, unsigned short* __restrict__ out) {
    __shared__ float tile[32][33];
    int bx = blockIdx.x;          // k tile
    int by = blockIdx.y;          // n tile
    int tx = threadIdx.x;         // 0..31
    int ty = threadIdx.y;         // 0..7
#pragma unroll
    for (int j = 0; j < 4; j++)
        tile[ty + j*8][tx] = W[(size_t)(bx*32 + ty + j*8) * 1024 + by*32 + tx];
    __syncthreads();
#pragma unroll
    for (int j = 0; j < 4; j++)
        out[(size_t)(by*32 + ty + j*8) * 1024 + bx*32 + tx] = f2bf(tile[tx][ty + j*8]);
}

// ---------- P2: transpose V (bf16): VT[b][n][m] = QKV[b*2048+m][2048+n] ----------
__global__ void vtrans_kernel(const unsigned short* __restrict__ qkv, unsigned short* __restrict__ vt) {
    __shared__ unsigned short tile[32][33];
    int b = blockIdx.z;
    const unsigned short* V = qkv + (size_t)b * 2048 * 3072 + 2048;
    unsigned short* out = vt + (size_t)b * 1024 * 2048;
    int bx = blockIdx.x;          // m tile (64 tiles)
    int by = blockIdx.y;          // n tile (32 tiles)
    int tx = threadIdx.x, ty = threadIdx.y;
#pragma unroll
    for (int j = 0; j < 4; j++)
        tile[ty + j*8][tx] = V[(size_t)(bx*32 + ty + j*8) * 3072 + by*32 + tx];
    __syncthreads();
#pragma unroll
    for (int j = 0; j < 4; j++)
        out[(size_t)(by*32 + ty + j*8) * 2048 + bx*32 + tx] = tile[tx][ty + j*8];
}

// ---------- softmax: one block per row of 2048 bf16, in place ----------
__global__ void softmax_kernel(unsigned short* __restrict__ S) {
    const size_t row = blockIdx.x;
    unsigned short* p = S + row * 2048;
    const int tid = threadIdx.x;
    const int wave = tid >> 6, lane = tid & 63;

    uint4 raw = ((const uint4*)p)[tid];   // 8 bf16 per thread
    unsigned u[4] = {raw.x, raw.y, raw.z, raw.w};
    float x[8];
#pragma unroll
    for (int i = 0; i < 4; i++) {
        x[2*i]   = __uint_as_float(u[i] << 16);
        x[2*i+1] = __uint_as_float(u[i] & 0xffff0000u);
    }
    float m = x[0];
#pragma unroll
    for (int i = 1; i < 8; i++) m = fmaxf(m, x[i]);
#pragma unroll
    for (int off = 32; off >= 1; off >>= 1) m = fmaxf(m, __shfl_xor(m, off, 64));
    __shared__ float sm[4], ss[4];
    if (lane == 0) sm[wave] = m;
    __syncthreads();
    m = fmaxf(fmaxf(sm[0], sm[1]), fmaxf(sm[2], sm[3]));

    float e[8], s = 0.f;
#pragma unroll
    for (int i = 0; i < 8; i++) { e[i] = __expf(x[i] - m); s += e[i]; }
#pragma unroll
    for (int off = 32; off >= 1; off >>= 1) s += __shfl_xor(s, off, 64);
    if (lane == 0) ss[wave] = s;
    __syncthreads();
    s = ss[0] + ss[1] + ss[2] + ss[3];
    float inv = 1.0f / s;

    unsigned o[4];
#pragma unroll
    for (int i = 0; i < 4; i++) {
        unsigned lo = f2bf(e[2*i] * inv);
        unsigned hi = f2bf(e[2*i+1] * inv);
        o[i] = lo | (hi << 16);
    }
    ((uint4*)p)[tid] = make_uint4(o[0], o[1], o[2], o[3]);
}

// ---------- NT GEMM: C[m][n] = scale * sum_k A[m][k] * B[n][k]  (+bias) ----------
// 128x128 block tile, BK=32, 4 waves each 64x64, 16x16x32 bf16 MFMA.
template<bool OUT_BF16, bool BIAS>
__global__ __launch_bounds__(256)
void gemm_nt(const unsigned short* __restrict__ A, const unsigned short* __restrict__ B,
             void* __restrict__ C, const float* __restrict__ bias,
             int lda, int ldb, int ldc, int nk, float scale,
             long long sA, long long sB, long long sC)
{
    __shared__ __align__(16) unsigned short As[128 * 32];
    __shared__ __align__(16) unsigned short Bs[128 * 32];

    const int tid  = threadIdx.x;
    const int lane = tid & 63;
    const int wave = tid >> 6;
    const int bz = blockIdx.z;
    A += (size_t)bz * sA;
    B += (size_t)bz * sB;
    const int bm = blockIdx.y * 128;
    const int bn = blockIdx.x * 128;

    // staging: per call each thread moves 16 B; call i covers tile rows [i*64, i*64+64)
    const int srow = tid >> 2;            // 0..63
    const int scol = (tid & 3) * 8;       // element offset 0/8/16/24
    const unsigned short* ga = A + (size_t)(bm + srow) * lda + scol;
    const unsigned short* gb = B + (size_t)(bn + srow) * ldb + scol;

    f32x4 acc[4][4];
#pragma unroll
    for (int i = 0; i < 4; i++)
#pragma unroll
        for (int j = 0; j < 4; j++) acc[i][j] = (f32x4){0.f, 0.f, 0.f, 0.f};

    const int wm = (wave & 1) * 64;
    const int wn = (wave >> 1) * 64;
    const int ln15 = lane & 15;
    const int quad = lane >> 4;
    const int fk = quad * 8;              // k offset of this lane's fragment

    for (int kt = 0; kt < nk; ++kt) {
        __syncthreads();
#pragma unroll
        for (int i = 0; i < 2; i++) {
            gld_lds16(ga + (size_t)i * 64 * lda, (unsigned short*)((char*)As + i*4096 + tid*16));
            gld_lds16(gb + (size_t)i * 64 * ldb, (unsigned short*)((char*)Bs + i*4096 + tid*16));
        }
        ga += 32; gb += 32;
        asm volatile("s_waitcnt vmcnt(0)" ::: "memory");
        __syncthreads();

        bf16x8 af[4], bfr[4];
#pragma unroll
        for (int i = 0; i < 4; i++)
            af[i] = *(const bf16x8*)&As[(wm + i*16 + ln15) * 32 + fk];
#pragma unroll
        for (int j = 0; j < 4; j++)
            bfr[j] = *(const bf16x8*)&Bs[(wn + j*16 + ln15) * 32 + fk];
#pragma unroll
        for (int i = 0; i < 4; i++)
#pragma unroll
            for (int j = 0; j < 4; j++)
                acc[i][j] = __builtin_amdgcn_mfma_f32_16x16x32_bf16(af[i], bfr[j], acc[i][j], 0, 0, 0);
    }

    // epilogue. C/D layout: col = lane&15, row = quad*4 + reg
    float bval[4];
    if (BIAS) {
#pragma unroll
        for (int j = 0; j < 4; j++) bval[j] = bias[bn + wn + j*16 + ln15];
    }
    unsigned short* Co16 = (unsigned short*)C + (size_t)bz * sC;
    float*          Co32 = (float*)C          + (size_t)bz * sC;
#pragma unroll
    for (int i = 0; i < 4; i++) {
        int r0 = bm + wm + i*16 + quad*4;
#pragma unroll
        for (int j = 0; j < 4; j++) {
            int c = bn + wn + j*16 + ln15;
#pragma unroll
            for (int r = 0; r < 4; r++) {
                float v = acc[i][j][r] * scale;
                if (OUT_BF16) Co16[(size_t)(r0 + r) * ldc + c] = f2bf(v);
                else          Co32[(size_t)(r0 + r) * ldc + c] = v + (BIAS ? bval[j] : 0.f);
            }
        }
    }
}

// ---------- launcher ----------
extern "C" void kernel_launch(void* const* d_in, const int* in_sizes, int n_in,
                              void* d_out, int out_size, void* d_ws, size_t ws_size,
                              hipStream_t stream) {
    const float* X  = (const float*)d_in[0];   // [4,2048,1024]
    const float* Wq = (const float*)d_in[1];   // [1024,1024]
    const float* Wk = (const float*)d_in[2];
    const float* Wv = (const float*)d_in[3];
    const float* Wo = (const float*)d_in[4];
    const float* bo = (const float*)d_in[5];   // [1024]
    float* out = (float*)d_out;

    // workspace layout (bf16 buffers as ushort)
    size_t off = 0;
    auto alloc = [&](size_t bytes) {
        void* p = (char*)d_ws + off;
        off += (bytes + 255) & ~(size_t)255;
        return p;
    };
    unsigned short* Xbf  = (unsigned short*)alloc(8192ull * 1024 * 2);   // 16 MB (reused as AO)
    unsigned short* Wcat = (unsigned short*)alloc(3072ull * 1024 * 2);   //  6 MB  [n][k], q/k/v stacked
    unsigned short* WoT  = (unsigned short*)alloc(1024ull * 1024 * 2);   //  2 MB  [n][k]
    unsigned short* QKV  = (unsigned short*)alloc(8192ull * 3072 * 2);   // 48 MB  [8192][3072]
    unsigned short* VT   = (unsigned short*)alloc(4ull * 1024 * 2048 * 2); // 16 MB [b][n][m]
    unsigned short* Sc   = (unsigned short*)alloc(4ull * 2048 * 2048 * 2); // 32 MB scores/probs
    unsigned short* AO   = Xbf;  // X dead after G1

    // P0: X -> bf16
    cvt_kernel<<<(8192*1024/4 + 255)/256, 256, 0, stream>>>(X, Xbf, 8192*1024/4);
    // P1: weight transposes
    dim3 tb(32, 8);
    wtrans_kernel<<<dim3(32,32), tb, 0, stream>>>(Wq, Wcat);
    wtrans_kernel<<<dim3(32,32), tb, 0, stream>>>(Wk, Wcat + 1024*1024);
    wtrans_kernel<<<dim3(32,32), tb, 0, stream>>>(Wv, Wcat + 2*1024*1024);
    wtrans_kernel<<<dim3(32,32), tb, 0, stream>>>(Wo, WoT);

    // G1: QKV = Xbf @ Wcat^T   M=8192 N=3072 K=1024
    gemm_nt<true,false><<<dim3(3072/128, 8192/128, 1), 256, 0, stream>>>(
        Xbf, Wcat, QKV, nullptr, 1024, 1024, 3072, 1024/32, 1.0f, 0, 0, 0);

    // P2: V -> VT
    vtrans_kernel<<<dim3(64, 32, 4), tb, 0, stream>>>(QKV, VT);

    // G2: Sc = (Q @ K^T) / 32  per batch   M=N=2048 K=1024
    gemm_nt<true,false><<<dim3(2048/128, 2048/128, 4), 256, 0, stream>>>(
        QKV, QKV + 1024, Sc, nullptr, 3072, 3072, 2048, 1024/32, 0.03125f,
        2048ll*3072, 2048ll*3072, 2048ll*2048);

    // softmax in place
    softmax_kernel<<<8192, 256, 0, stream>>>(Sc);

    // G3: AO = P @ V  per batch   M=2048 N=1024 K=2048
    gemm_nt<true,false><<<dim3(1024/128, 2048/128, 4), 256, 0, stream>>>(
        Sc, VT, AO, nullptr, 2048, 2048, 1024, 2048/32, 1.0f,
        2048ll*2048, 1024ll*2048, 2048ll*1024);

    // G4: out = AO @ WoT^T + bo   M=8192 N=1024 K=1024, fp32 out
    gemm_nt<false,true><<<dim3(1024/128, 8192/128, 1), 256, 0, stream>>>(
        AO, WoT, out, bo, 1024, 1024, 1024, 1024/32, 1.0f, 0, 0, 0);

    (void)n_in; (void)in_sizes; (void)out_size; (void)ws_size;
}